// Round 2
// baseline (158.333 us; speedup 1.0000x reference)
//
#include <hip/hip_runtime.h>
#include <math.h>

#define B_TOT 16384
#define S_    7
#define M_    16
#define C_    30
#define NC_   20
#define CELLS (S_*S_)        // 49
#define PER_B (CELLS*C_)     // 1470 floats = 5880 B per batch
#define GPB   16             // batches per block; 16*1470*4 = 94080 B, 16B-aligned
#define BLK   256
#define NBLK  (B_TOT/GPB)    // 1024

__device__ __forceinline__ float iou_cf(float ax,float ay,float aw,float ah,
                                        float bx,float by,float bw,float bh){
  float ax1=ax-aw*0.5f, ay1=ay-ah*0.5f, ax2=ax+aw*0.5f, ay2=ay+ah*0.5f;
  float bx1=bx-bw*0.5f, by1=by-bh*0.5f, bx2=bx+bw*0.5f, by2=by+bh*0.5f;
  float iw=fmaxf(fminf(ax2,bx2)-fmaxf(ax1,bx1), 0.f);
  float ih=fmaxf(fminf(ay2,by2)-fmaxf(ay1,by1), 0.f);
  float inter=iw*ih;
  float uni=aw*ah+bw*bh-inter;
  return inter/(uni+1e-6f);
}

__global__ __launch_bounds__(BLK) void yolo_fused(const float* __restrict__ pred,
                                                  const float* __restrict__ gt_xywh,
                                                  const int*   __restrict__ gt_class,
                                                  float*       __restrict__ out)
{
  const int t   = threadIdx.x;
  const int blk = blockIdx.x;
  const int base_b = blk * GPB;

  // ---- per-box info: every thread owns exactly one (batch, m) box ----
  const int lb = t >> 4;      // local batch 0..15
  const int m  = t & 15;      // box index 0..15
  // gt_xywh[(base_b+lb)*16 + m] == flat index blk*256 + t  -> coalesced float4
  float4 g = ((const float4*)gt_xywh)[blk*BLK + t];
  // NOTE reference quirk: row from x, col from y (kept faithfully)
  int row = (int)floorf(g.x * (float)S_); row = min(max(row,0), S_-1);
  int col = (int)floorf(g.y * (float)S_); col = min(max(col,0), S_-1);
  const int cell = row*S_ + col;
  const float tx = g.x*(float)S_ - (float)col;   // x uses col, y uses row (as in ref)
  const float ty = g.y*(float)S_ - (float)row;
  const float tw = sqrtf(g.z);
  const float th = sqrtf(g.w);
  const int cls  = gt_class[blk*BLK + t];
  // first-occurrence-per-cell dedup within the 16-lane group (one batch)
  bool keep = true;
  #pragma unroll
  for (int j = 0; j < M_; ++j) {
    int cj = __shfl(cell, j, M_);
    if (j < m && cj == cell) keep = false;
  }

  // ---- streaming scan: sum conf^2 (channels 4,9) over ALL cells of the slab ----
  float accn = 0.f;
  const float4* s4 = (const float4*)(pred + (size_t)base_b * PER_B);
  const int n4 = GPB*PER_B/4;           // 5880 float4 per block
  int c0 = (t*4) % 30;                  // channel of elem 0 of this thread's first float4
  for (int i = t; i < n4; i += BLK) {
    float4 v = s4[i];
    float vv[4] = {v.x, v.y, v.z, v.w};
    #pragma unroll
    for (int k = 0; k < 4; ++k) {
      int c = c0 + k; if (c >= 30) c -= 30;
      if (c == 4 || c == 9) accn += vv[k]*vv[k];
    }
    c0 += 4; if (c0 >= 30) c0 -= 30;    // stride 4*BLK=1024 floats ≡ +4 (mod 30)
  }

  // ---- object-cell terms (gathers hit L1/L2: this block just streamed them) ----
  float accb = 0.f;
  if (keep) {
    const float* cp = pred + (size_t)(base_b + lb) * PER_B + cell*C_;
    float p0=cp[0],p1=cp[1],p2=cp[2],p3=cp[3],p4=cp[4];
    float p5=cp[5],p6=cp[6],p7=cp[7],p8=cp[8],p9=cp[9];
    float i1 = iou_cf(p0,p1,p2,p3, tx,ty,tw,th);
    float i2 = iou_cf(p5,p6,p7,p8, tx,ty,tw,th);
    bool  u2 = (i2 >= i1);                       // ties -> second box
    float sx = u2?p5:p0, sy = u2?p6:p1, sw = u2?p7:p2, sh = u2?p8:p3;
    float sc = u2?p9:p4, si = u2?i2:i1;
    float dx=sx-tx, dy=sy-ty, dw=sw-tw, dh=sh-th;
    accb += 5.0f*(dx*dx + dy*dy + dw*dw + dh*dh);        // LAMBDA_COORD
    float dc = sc - si;
    accb += dc*dc;
    #pragma unroll
    for (int c = 0; c < NC_; ++c) {
      float d = cp[10+c] - ((c==cls) ? 1.f : 0.f);
      accb += d*d;
    }
    // kept boxes' cells == obj cells (distinct): cancel their conf^2 from the scan
    accb -= 0.5f*(p4*p4 + p9*p9);
  }

  float acc = accb + 0.5f*accn;                          // LAMBDA_NOOBJ on scan part

  // ---- block reduction: wave shuffle + LDS, then one atomic per block ----
  #pragma unroll
  for (int off = 32; off > 0; off >>= 1) acc += __shfl_down(acc, off);
  __shared__ float wsum[BLK/64];
  if ((t & 63) == 0) wsum[t >> 6] = acc;
  __syncthreads();
  if (t == 0) {
    float v = (wsum[0] + wsum[1] + wsum[2] + wsum[3]) * (1.0f/(float)B_TOT);
    atomicAdd(out, v);   // device-scope by default on CDNA4; out zeroed by memset below
  }
}

extern "C" void kernel_launch(void* const* d_in, const int* in_sizes, int n_in,
                              void* d_out, int out_size, void* d_ws, size_t ws_size,
                              hipStream_t stream) {
  const float* pred     = (const float*)d_in[0];
  const float* gt_xywh  = (const float*)d_in[1];
  const int*   gt_class = (const int*)d_in[2];
  (void)d_ws; (void)ws_size;
  // d_out is re-poisoned to 0xAA before every timed launch -> zero it ourselves.
  hipMemsetAsync(d_out, 0, sizeof(float), stream);
  yolo_fused<<<NBLK, BLK, 0, stream>>>(pred, gt_xywh, gt_class, (float*)d_out);
}

// Round 3
// 153.642 us; speedup vs baseline: 1.0305x; 1.0305x over previous
//
#include <hip/hip_runtime.h>
#include <math.h>

#define B_TOT 16384
#define S_    7
#define M_    16
#define C_    30
#define NC_   20
#define CELLS (S_*S_)        // 49
#define PER_B (CELLS*C_)     // 1470 floats = 5880 B per batch
#define GPB   8              // batches per block; 8*1470*4 = 47040 B
#define BLK   256
#define NBLK  (B_TOT/GPB)    // 2048

__device__ __forceinline__ float iou_cf(float ax,float ay,float aw,float ah,
                                        float bx,float by,float bw,float bh){
  float ax1=ax-aw*0.5f, ay1=ay-ah*0.5f, ax2=ax+aw*0.5f, ay2=ay+ah*0.5f;
  float bx1=bx-bw*0.5f, by1=by-bh*0.5f, bx2=bx+bw*0.5f, by2=by+bh*0.5f;
  float iw=fmaxf(fminf(ax2,bx2)-fmaxf(ax1,bx1), 0.f);
  float ih=fmaxf(fminf(ay2,by2)-fmaxf(ay1,by1), 0.f);
  float inter=iw*ih;
  float uni=aw*ah+bw*bh-inter;
  return inter/(uni+1e-6f);
}

__global__ __launch_bounds__(BLK) void yolo_main(const float* __restrict__ pred,
                                                 const float* __restrict__ gt_xywh,
                                                 const int*   __restrict__ gt_class,
                                                 float*       __restrict__ partial)
{
  const int t   = threadIdx.x;
  const int blk = blockIdx.x;
  const int base_b = blk * GPB;

  // ---- per-box info (threads 0..127 own one (batch, m) box each) ----
  int   cell = 0, cls = 0;
  bool  keep = false;
  float tx=0.f, ty=0.f, tw=0.f, th=0.f;
  const int lb = t >> 4;      // local batch 0..7
  const int m  = t & 15;      // box index 0..15
  if (t < GPB*M_) {
    float4 g = ((const float4*)gt_xywh)[base_b*M_ + t];   // coalesced float4
    // NOTE reference quirk: row from x, col from y (kept faithfully)
    int row = (int)floorf(g.x * (float)S_); row = min(max(row,0), S_-1);
    int col = (int)floorf(g.y * (float)S_); col = min(max(col,0), S_-1);
    cell = row*S_ + col;
    tx = g.x*(float)S_ - (float)col;   // x uses col, y uses row (as in reference)
    ty = g.y*(float)S_ - (float)row;
    tw = sqrtf(g.z);
    th = sqrtf(g.w);
    cls  = gt_class[base_b*M_ + t];
    keep = true;
    // first-occurrence-per-cell dedup within the 16-lane group (one batch)
    #pragma unroll
    for (int j = 0; j < M_; ++j) {
      int cj = __shfl(cell, j, M_);
      if (j < m && cj == cell) keep = false;
    }
  }

  // ---- streaming scan of the whole slab for the noobj conf^2 term ----
  // Channel residue c0 = (4*i) mod 30 is even; a float4 spans 4 channels, so
  // at most ONE component can be ch4 or ch9, and only at residues:
  //   c0==2 -> .z is ch4 | c0==4 -> .x is ch4 | c0==6 -> .w is ch9 | c0==8 -> .y is ch9
  // (mod-30 wrap inside a float4 can only yield c in {0,1} — never 4/9).
  float accn = 0.f;
  const float4* s4 = (const float4*)(pred + (size_t)base_b * PER_B);
  const int n4 = GPB*PER_B/4;           // 2940 float4 per block
  int c0 = (t*4) % 30;
  for (int i = t; i < n4; i += BLK) {
    float4 v = s4[i];
    float sv = (c0==2) ? v.z : (c0==4) ? v.x : (c0==6) ? v.w : (c0==8) ? v.y : 0.f;
    accn += sv*sv;
    c0 += 4; if (c0 >= 30) c0 -= 30;    // stride 4*BLK=1024 floats ≡ +4 (mod 30)
  }

  // ---- object-cell terms (gathers hit L1/L2: this block just streamed them) ----
  float accb = 0.f;
  if (keep) {
    const float* cp = pred + (size_t)(base_b + lb) * PER_B + cell*C_;
    float p0=cp[0],p1=cp[1],p2=cp[2],p3=cp[3],p4=cp[4];
    float p5=cp[5],p6=cp[6],p7=cp[7],p8=cp[8],p9=cp[9];
    float i1 = iou_cf(p0,p1,p2,p3, tx,ty,tw,th);
    float i2 = iou_cf(p5,p6,p7,p8, tx,ty,tw,th);
    bool  u2 = (i2 >= i1);                       // ties -> second box
    float sx = u2?p5:p0, sy = u2?p6:p1, sw = u2?p7:p2, sh = u2?p8:p3;
    float sc = u2?p9:p4, si = u2?i2:i1;
    float dx=sx-tx, dy=sy-ty, dw=sw-tw, dh=sh-th;
    accb += 5.0f*(dx*dx + dy*dy + dw*dw + dh*dh);        // LAMBDA_COORD
    float dc = sc - si;
    accb += dc*dc;
    #pragma unroll
    for (int c = 0; c < NC_; ++c) {
      float d = cp[10+c] - ((c==cls) ? 1.f : 0.f);
      accb += d*d;
    }
    // kept boxes' cells == obj cells (distinct): cancel their conf^2 from the scan
    accb -= 0.5f*(p4*p4 + p9*p9);
  }

  float acc = accb + 0.5f*accn;                          // LAMBDA_NOOBJ on scan part

  // ---- block reduction: wave shuffle + LDS, one partial per block ----
  #pragma unroll
  for (int off = 32; off > 0; off >>= 1) acc += __shfl_down(acc, off);
  __shared__ float wsum[BLK/64];
  if ((t & 63) == 0) wsum[t >> 6] = acc;
  __syncthreads();
  if (t == 0) partial[blk] = wsum[0] + wsum[1] + wsum[2] + wsum[3];
}

__global__ __launch_bounds__(256) void yolo_reduce(const float* __restrict__ partial,
                                                   float* __restrict__ out)
{
  const int t = threadIdx.x;
  float a = 0.f;
  #pragma unroll
  for (int i = t; i < NBLK; i += 256) a += partial[i];
  #pragma unroll
  for (int off = 32; off > 0; off >>= 1) a += __shfl_down(a, off);
  __shared__ float wsum[4];
  if ((t & 63) == 0) wsum[t >> 6] = a;
  __syncthreads();
  if (t == 0) out[0] = (wsum[0] + wsum[1] + wsum[2] + wsum[3]) * (1.0f/(float)B_TOT);
}

extern "C" void kernel_launch(void* const* d_in, const int* in_sizes, int n_in,
                              void* d_out, int out_size, void* d_ws, size_t ws_size,
                              hipStream_t stream) {
  const float* pred     = (const float*)d_in[0];
  const float* gt_xywh  = (const float*)d_in[1];
  const int*   gt_class = (const int*)d_in[2];
  float* partial = (float*)d_ws;                 // NBLK floats = 8 KB scratch
  yolo_main<<<NBLK, BLK, 0, stream>>>(pred, gt_xywh, gt_class, partial);
  yolo_reduce<<<1, 256, 0, stream>>>(partial, (float*)d_out);
}

// Round 4
// 150.466 us; speedup vs baseline: 1.0523x; 1.0211x over previous
//
#include <hip/hip_runtime.h>
#include <math.h>

#define B_TOT 16384
#define S_    7
#define M_    16
#define C_    30
#define NC_   20
#define CELLS (S_*S_)        // 49
#define PER_B (CELLS*C_)     // 1470 floats = 5880 B per batch
#define GPB   4              // batches per block; 4*1470*4 = 23520 B slab
#define BLK   256
#define NBLK  (B_TOT/GPB)    // 4096 blocks -> 16 blocks/CU oversubscription

__device__ __forceinline__ float iou_cf(float ax,float ay,float aw,float ah,
                                        float bx,float by,float bw,float bh){
  float ax1=ax-aw*0.5f, ay1=ay-ah*0.5f, ax2=ax+aw*0.5f, ay2=ay+ah*0.5f;
  float bx1=bx-bw*0.5f, by1=by-bh*0.5f, bx2=bx+bw*0.5f, by2=by+bh*0.5f;
  float iw=fmaxf(fminf(ax2,bx2)-fmaxf(ax1,bx1), 0.f);
  float ih=fmaxf(fminf(ay2,by2)-fmaxf(ay1,by1), 0.f);
  float inter=iw*ih;
  float uni=aw*ah+bw*bh-inter;
  return inter/(uni+1e-6f);
}

__global__ __launch_bounds__(BLK) void yolo_main(const float* __restrict__ pred,
                                                 const float* __restrict__ gt_xywh,
                                                 const int*   __restrict__ gt_class,
                                                 float*       __restrict__ partial)
{
  const int t   = threadIdx.x;
  const int blk = blockIdx.x;
  const int base_b = blk * GPB;

  // ---- per-box info (threads 0..63 own one (batch, m) box each) ----
  int   cell = 0, cls = 0;
  bool  keep = false;
  float tx=0.f, ty=0.f, tw=0.f, th=0.f;
  const int lb = t >> 4;      // local batch 0..3
  const int m  = t & 15;      // box index 0..15
  if (t < GPB*M_) {
    float4 g = ((const float4*)gt_xywh)[base_b*M_ + t];   // coalesced float4
    // NOTE reference quirk: row from x, col from y (kept faithfully)
    int row = (int)floorf(g.x * (float)S_); row = min(max(row,0), S_-1);
    int col = (int)floorf(g.y * (float)S_); col = min(max(col,0), S_-1);
    cell = row*S_ + col;
    tx = g.x*(float)S_ - (float)col;   // x uses col, y uses row (as in reference)
    ty = g.y*(float)S_ - (float)row;
    tw = sqrtf(g.z);
    th = sqrtf(g.w);
    cls  = gt_class[base_b*M_ + t];
    keep = true;
    // first-occurrence-per-cell dedup within the 16-lane group (one batch)
    #pragma unroll
    for (int j = 0; j < M_; ++j) {
      int cj = __shfl(cell, j, M_);
      if (j < m && cj == cell) keep = false;
    }
  }

  // ---- streaming scan of the whole slab for the noobj conf^2 term ----
  // Channel residue c0 = (4*i) mod 30 is even; a float4 spans 4 channels, so
  // at most ONE component can be ch4 or ch9, and only at residues:
  //   c0==2 -> .z is ch4 | c0==4 -> .x is ch4 | c0==6 -> .w is ch9 | c0==8 -> .y is ch9
  // (mod-30 wrap inside a float4 can only yield c in {0,1} — never 4/9).
  float accn = 0.f;
  const float4* s4 = (const float4*)(pred + (size_t)base_b * PER_B);
  const int n4 = GPB*PER_B/4;           // 1470 float4 per block
  int c0 = (t*4) % 30;
  for (int i = t; i < n4; i += BLK) {
    float4 v = s4[i];
    float sv = (c0==2) ? v.z : (c0==4) ? v.x : (c0==6) ? v.w : (c0==8) ? v.y : 0.f;
    accn = fmaf(sv, sv, accn);
    c0 += 4; if (c0 >= 30) c0 -= 30;    // stride 4*BLK=1024 floats ≡ +4 (mod 30)
  }

  // ---- object-cell terms (gathers hit L1/L2: this block just streamed them) ----
  float accb = 0.f;
  if (keep) {
    const float* cp = pred + (size_t)(base_b + lb) * PER_B + cell*C_;
    float p0=cp[0],p1=cp[1],p2=cp[2],p3=cp[3],p4=cp[4];
    float p5=cp[5],p6=cp[6],p7=cp[7],p8=cp[8],p9=cp[9];
    float i1 = iou_cf(p0,p1,p2,p3, tx,ty,tw,th);
    float i2 = iou_cf(p5,p6,p7,p8, tx,ty,tw,th);
    bool  u2 = (i2 >= i1);                       // ties -> second box
    float sx = u2?p5:p0, sy = u2?p6:p1, sw = u2?p7:p2, sh = u2?p8:p3;
    float sc = u2?p9:p4, si = u2?i2:i1;
    float dx=sx-tx, dy=sy-ty, dw=sw-tw, dh=sh-th;
    accb += 5.0f*(dx*dx + dy*dy + dw*dw + dh*dh);        // LAMBDA_COORD
    float dc = sc - si;
    accb += dc*dc;
    #pragma unroll
    for (int c = 0; c < NC_; ++c) {
      float d = cp[10+c] - ((c==cls) ? 1.f : 0.f);
      accb += d*d;
    }
    // kept boxes' cells == obj cells (distinct): cancel their conf^2 from the scan
    accb -= 0.5f*(p4*p4 + p9*p9);
  }

  float acc = accb + 0.5f*accn;                          // LAMBDA_NOOBJ on scan part

  // ---- block reduction: wave shuffle + LDS, one partial per block ----
  #pragma unroll
  for (int off = 32; off > 0; off >>= 1) acc += __shfl_down(acc, off);
  __shared__ float wsum[BLK/64];
  if ((t & 63) == 0) wsum[t >> 6] = acc;
  __syncthreads();
  if (t == 0) partial[blk] = wsum[0] + wsum[1] + wsum[2] + wsum[3];
}

__global__ __launch_bounds__(256) void yolo_reduce(const float* __restrict__ partial,
                                                   float* __restrict__ out)
{
  const int t = threadIdx.x;
  float a = 0.f;
  const float4* p4 = (const float4*)partial;
  #pragma unroll
  for (int i = t; i < NBLK/4; i += 256) {
    float4 v = p4[i];
    a += (v.x + v.y) + (v.z + v.w);
  }
  #pragma unroll
  for (int off = 32; off > 0; off >>= 1) a += __shfl_down(a, off);
  __shared__ float wsum[4];
  if ((t & 63) == 0) wsum[t >> 6] = a;
  __syncthreads();
  if (t == 0) out[0] = (wsum[0] + wsum[1] + wsum[2] + wsum[3]) * (1.0f/(float)B_TOT);
}

extern "C" void kernel_launch(void* const* d_in, const int* in_sizes, int n_in,
                              void* d_out, int out_size, void* d_ws, size_t ws_size,
                              hipStream_t stream) {
  const float* pred     = (const float*)d_in[0];
  const float* gt_xywh  = (const float*)d_in[1];
  const int*   gt_class = (const int*)d_in[2];
  float* partial = (float*)d_ws;                 // NBLK floats = 16 KB scratch
  yolo_main<<<NBLK, BLK, 0, stream>>>(pred, gt_xywh, gt_class, partial);
  yolo_reduce<<<1, 256, 0, stream>>>(partial, (float*)d_out);
}